// Round 5
// baseline (228.972 us; speedup 1.0000x reference)
//
#include <hip/hip_runtime.h>
#include <hip/hip_cooperative_groups.h>
#include <math.h>

namespace cg = cooperative_groups;

#define BATCH   512
#define IN_DIM  4096
#define HID_DIM 8192
#define OUT_DIM 1024
#define T_STEPS 10
#define LEAK    0.95f

// ===========================================================================
// Single cooperative kernel, 512 blocks x 256 threads (2 blocks/CU — safely
// co-resident: ~1.5 KB LDS, low VGPR).
//
// Exactness argument (validated by absmax=0.0 in rounds 3-4):
//  * REFRACT=1 and current_time=spike_count imply each neuron spikes AT MOST
//    ONCE EVER (after a spike t-last==1 forever, never >1); adaptation
//    (count>10) is unreachable. So per-neuron output = index of first batch
//    whose constant current drives v over threshold within 10 leaky steps.
//  * Hidden neurons are mutually independent given x: per-column decisions
//    are exact. Weights are >=0 (clip[0,1]) and rates>0, so a 64-row partial
//    sum LOWER-BOUNDS the b=0 current. Fires at b=0 iff
//    c >= (1-LEAK)/(1-LEAK^10) = 0.12461; we test lb >= 0.125 (E[lb]~16,
//    ~128x margin). lb pass => bfire_h=0 exactly. lb fail => full exact
//    per-column scan over all batches (slow; never taken on bench data).
//  * Output layer: if ALL hidden fired at b=0 (AND of hflags), then
//    c_o(0) = 0.1*colsum(W_ho), c_o(b>0) = 0 (v only decays after b=0), so
//    bo in {0,-1} decided per column: lb pass => 0; lb fail => exact full
//    colsum + 10-step simulation. If hidden flags don't all pass: exact
//    (slow) output fallback from bfire_h. All verdict buffers are fully
//    rewritten every launch before being read (poison-safe, no arming).
// ===========================================================================
__global__ __launch_bounds__(256) void snn_fused(const float* __restrict__ x,
                                                 const float* __restrict__ Wih,
                                                 const float* __restrict__ Who,
                                                 float* __restrict__ out,
                                                 int* __restrict__ bfire_h,
                                                 int* __restrict__ hflag,
                                                 int* __restrict__ bo_fast) {
    cg::grid_group grid = cg::this_grid();
    __shared__ float rs[64];
    __shared__ float red[16][17];
    __shared__ int colok[16];
    __shared__ int vote[4];

    const int g = blockIdx.x;    // 512
    const int t = threadIdx.x;   // 256
    const int tx = t & 15;
    const int ty = t >> 4;

    // ---- phase 1a: hidden check, 16 cols per block, rows 0..63 ----
    if (t < 64) rs[t] = 1.f / (1.f + __expf(-x[t]));   // rates of x row 0
    __syncthreads();
    {
        const int col = g * 16 + tx;
        float p = 0.f;
#pragma unroll
        for (int rr = 0; rr < 4; ++rr) {
            int r = ty * 4 + rr;
            p += rs[r] * Wih[(size_t)r * HID_DIM + col];
        }
        red[ty][tx] = p;
    }
    __syncthreads();
    if (t < 16) {
        const int col = g * 16 + t;
        float c = 0.f;
#pragma unroll
        for (int y = 0; y < 16; ++y) c += red[y][t];
        int bf;
        if (c >= 0.125f) {
            bf = 0;                                     // fires at b=0, exactly
        } else {
            // exact per-column scan, persistent state (rare; perf irrelevant)
            float v = 0.f;
            bf = -1;
            for (int b = 0; b < BATCH && bf < 0; ++b) {
                float cc = 0.f;
                for (int i = 0; i < IN_DIM; ++i)
                    cc += (1.f / (1.f + __expf(-x[(size_t)b * IN_DIM + i]))) *
                          Wih[(size_t)i * HID_DIM + col];
                for (int s = 0; s < T_STEPS; ++s) {
                    v = v * LEAK + cc;
                    if (v >= 1.0f) { bf = b; break; }   // single-spike structure
                }
            }
        }
        bfire_h[col] = bf;
        colok[t] = (bf == 0);
    }
    __syncthreads();
    if (t == 0) {
        int f = 1;
#pragma unroll
        for (int i = 0; i < 16; ++i) f &= colok[i];
        hflag[g] = f;
    }
    __syncthreads();                                    // red[] reuse guard

    // ---- phase 1b: speculative output verdicts (blocks 0..63, 16 cols) ----
    if (g < 64) {
        const int k = g * 16 + tx;
        float p = 0.f;
#pragma unroll
        for (int rr = 0; rr < 4; ++rr) {
            int r = ty * 4 + rr;
            p += Who[(size_t)r * OUT_DIM + k];
        }
        red[ty][tx] = p;
    }
    __syncthreads();
    if (g < 64 && t < 16) {
        const int k = g * 16 + t;
        float c = 0.f;
#pragma unroll
        for (int y = 0; y < 16; ++y) c += red[y][t];
        int bo;
        if (0.1f * c >= 0.125f) {
            bo = 0;
        } else {
            // exact: full colsum + simulation (valid under all-hidden-at-b0)
            float cs = 0.f;
            for (int j = 0; j < HID_DIM; ++j) cs += Who[(size_t)j * OUT_DIM + k];
            cs *= 0.1f;
            float v = 0.f;
            bo = -1;
#pragma unroll
            for (int s = 0; s < T_STEPS; ++s) {
                v = v * LEAK + cs;
                if (v >= 1.0f) { bo = 0; break; }
            }
        }
        bo_fast[k] = bo;
    }

    grid.sync();

    // ---- phase 2: global verdict + output write (block g owns row g) ----
    {
        int f = hflag[t] & hflag[t + 256];
        int aw = __all(f);
        if ((t & 63) == 0) vote[t >> 6] = aw;
    }
    __syncthreads();
    const int allh = vote[0] & vote[1] & vote[2] & vote[3];

    if (allh) {
        // bo_fast IS the exact bfire_o in this regime; coalesced 2 MB write
        int4 bo = ((const int4*)bo_fast)[t];
        float4 val;
        val.x = (bo.x == g) ? 0.1f : 0.f;
        val.y = (bo.y == g) ? 0.1f : 0.f;
        val.z = (bo.z == g) ? 0.1f : 0.f;
        val.w = (bo.w == g) ? 0.1f : 0.f;
        ((float4*)out)[(size_t)g * 256 + t] = val;
        return;
    }

    // exact output fallback from bfire_h (slow; never runs on passing data)
    for (int kq = 0; kq < 4; ++kq) {
        const int k = t * 4 + kq;
        float v = 0.f;
        int bo = -1;
        for (int b = 0; b < BATCH && bo < 0; ++b) {
            float c = 0.f;
            for (int j = 0; j < HID_DIM; ++j)
                c += (bfire_h[j] == b) ? Who[(size_t)j * OUT_DIM + k] : 0.f;
            c *= 0.1f;
            for (int s = 0; s < T_STEPS; ++s) {
                v = v * LEAK + c;
                if (v >= 1.0f) { bo = b; break; }
            }
        }
        out[(size_t)g * OUT_DIM + k] = (bo == g) ? 0.1f : 0.f;
    }
}

// ---------------------------------------------------------------------------
extern "C" void kernel_launch(void* const* d_in, const int* in_sizes, int n_in,
                              void* d_out, int out_size, void* d_ws, size_t ws_size,
                              hipStream_t stream) {
    const float* x    = (const float*)d_in[0];  // [512, 4096]
    const float* W_ih = (const float*)d_in[1];  // [4096, 8192]
    const float* W_ho = (const float*)d_in[2];  // [8192, 1024]
    float* out = (float*)d_out;                 // [512, 1024] fp32

    char* base = (char*)d_ws;
    int* bfire_h = (int*)(base + 29360128);     // 32 KB  (rewritten each launch)
    int* hflag   = (int*)(base + 29393920);     // 2 KB
    int* bo_fast = (int*)(base + 29396992);     // 4 KB

    void* args[] = { (void*)&x, (void*)&W_ih, (void*)&W_ho, (void*)&out,
                     (void*)&bfire_h, (void*)&hflag, (void*)&bo_fast };
    hipLaunchCooperativeKernel((const void*)snn_fused, dim3(512), dim3(256),
                               args, 0, stream);
}

// Round 6
// 180.544 us; speedup vs baseline: 1.2682x; 1.2682x over previous
//
#include <hip/hip_runtime.h>
#include <math.h>

#define BATCH   512
#define IN_DIM  4096
#define HID_DIM 8192
#define OUT_DIM 1024
#define T_STEPS 10
#define LEAK    0.95f

// ===========================================================================
// Two plain dispatches (coop launch measured +45 us in round 5 — reverted).
//
// Exactness argument (validated by absmax=0.0 in rounds 3-5):
//  * REFRACT=1 and current_time=spike_count imply each neuron spikes AT MOST
//    ONCE EVER (after a spike t-last==1 forever, never >1); adaptation
//    (count>10) is unreachable. Per-neuron output = index of first batch
//    whose constant current drives v over threshold within 10 leaky steps.
//  * Hidden neurons are independent given x: per-column decisions are exact.
//    Weights >= 0 (clip[0,1]) and rates > 0, so a 64-row partial sum
//    LOWER-BOUNDS the b=0 current. Fires at b=0 iff
//    c >= (1-LEAK)/(1-LEAK^10) = 0.12461; we test lb >= 0.125 (E[lb]~16,
//    ~128x margin). lb pass => bfire_h=0 exactly. lb fail => exact
//    per-column scan over all batches (slow; never taken on bench data).
//  * Output layer: if ALL hidden fired at b=0, c_o(0) = 0.1*colsum(W_ho)
//    and c_o(b>0) = 0, so bfire_o in {0,-1} per column: lb pass => 0;
//    lb fail => exact full colsum + 10-step simulation. If hidden flags
//    don't all pass: exact slow output fallback from bfire_h.
//  * hflag/bo_fast/bfire_h fully rewritten every launch before being read
//    (poison-safe, no arming, no atomics).
// ===========================================================================

// ---- dispatch 1: hidden resolve + hflag + speculative output verdicts ----
__global__ __launch_bounds__(256) void hidden_k(const float* __restrict__ x,
                                                const float* __restrict__ Wih,
                                                const float* __restrict__ Who,
                                                int* __restrict__ bfire_h,
                                                int* __restrict__ hflag,
                                                int* __restrict__ bo_fast) {
    __shared__ float rs[64];
    __shared__ float red[16][17];
    __shared__ int colok[16];

    const int g = blockIdx.x;    // 512
    const int t = threadIdx.x;   // 256
    const int tx = t & 15;
    const int ty = t >> 4;

    // hidden check: 16 cols per block, rows 0..63 of W_ih
    if (t < 64) rs[t] = 1.f / (1.f + __expf(-x[t]));   // rates of x row 0
    __syncthreads();
    {
        const int col = g * 16 + tx;
        float p = 0.f;
#pragma unroll
        for (int rr = 0; rr < 4; ++rr) {
            int r = ty * 4 + rr;
            p += rs[r] * Wih[(size_t)r * HID_DIM + col];
        }
        red[ty][tx] = p;
    }
    __syncthreads();
    if (t < 16) {
        const int col = g * 16 + t;
        float c = 0.f;
#pragma unroll
        for (int y = 0; y < 16; ++y) c += red[y][t];
        int bf;
        if (c >= 0.125f) {
            bf = 0;                                     // fires at b=0, exactly
        } else {
            // exact per-column scan, persistent state (never taken on bench)
            float v = 0.f;
            bf = -1;
            for (int b = 0; b < BATCH && bf < 0; ++b) {
                float cc = 0.f;
                for (int i = 0; i < IN_DIM; ++i)
                    cc += (1.f / (1.f + __expf(-x[(size_t)b * IN_DIM + i]))) *
                          Wih[(size_t)i * HID_DIM + col];
                for (int s = 0; s < T_STEPS; ++s) {
                    v = v * LEAK + cc;
                    if (v >= 1.0f) { bf = b; break; }   // single-spike structure
                }
            }
        }
        bfire_h[col] = bf;
        colok[t] = (bf == 0);
    }
    __syncthreads();
    if (t == 0) {
        int f = 1;
#pragma unroll
        for (int i = 0; i < 16; ++i) f &= colok[i];
        hflag[g] = f;
    }

    // speculative output verdicts (blocks 0..63 own 16 cols each)
    if (g >= 64) return;
    __syncthreads();                                    // red[] reuse guard
    {
        const int k = g * 16 + tx;
        float p = 0.f;
#pragma unroll
        for (int rr = 0; rr < 4; ++rr) {
            int r = ty * 4 + rr;
            p += Who[(size_t)r * OUT_DIM + k];
        }
        red[ty][tx] = p;
    }
    __syncthreads();
    if (t < 16) {
        const int k = g * 16 + t;
        float c = 0.f;
#pragma unroll
        for (int y = 0; y < 16; ++y) c += red[y][t];
        int bo;
        if (0.1f * c >= 0.125f) {
            bo = 0;
        } else {
            // exact: full colsum + simulation (valid under all-hidden-at-b0)
            float cs = 0.f;
            for (int j = 0; j < HID_DIM; ++j) cs += Who[(size_t)j * OUT_DIM + k];
            cs *= 0.1f;
            float v = 0.f;
            bo = -1;
#pragma unroll
            for (int s = 0; s < T_STEPS; ++s) {
                v = v * LEAK + cs;
                if (v >= 1.0f) { bo = 0; break; }
            }
        }
        bo_fast[k] = bo;
    }
}

// ---- dispatch 2: global verdict + output write (block g owns row g) ----
__global__ __launch_bounds__(256) void final_k(const float* __restrict__ Who,
                                               const int* __restrict__ bfire_h,
                                               const int* __restrict__ hflag,
                                               const int* __restrict__ bo_fast,
                                               float* __restrict__ out) {
    __shared__ int vote[4];
    const int g = blockIdx.x;    // 512
    const int t = threadIdx.x;   // 256
    {
        int f = hflag[t] & hflag[t + 256];
        int aw = __all(f);
        if ((t & 63) == 0) vote[t >> 6] = aw;
    }
    __syncthreads();
    const int allh = vote[0] & vote[1] & vote[2] & vote[3];

    if (allh) {
        // bo_fast IS the exact bfire_o in this regime; coalesced 2 MB write
        int4 bo = ((const int4*)bo_fast)[t];
        float4 val;
        val.x = (bo.x == g) ? 0.1f : 0.f;
        val.y = (bo.y == g) ? 0.1f : 0.f;
        val.z = (bo.z == g) ? 0.1f : 0.f;
        val.w = (bo.w == g) ? 0.1f : 0.f;
        ((float4*)out)[(size_t)g * 256 + t] = val;
        return;
    }

    // exact output fallback from bfire_h (slow; never runs on passing data)
    for (int kq = 0; kq < 4; ++kq) {
        const int k = t * 4 + kq;
        float v = 0.f;
        int bo = -1;
        for (int b = 0; b < BATCH && bo < 0; ++b) {
            float c = 0.f;
            for (int j = 0; j < HID_DIM; ++j)
                c += (bfire_h[j] == b) ? Who[(size_t)j * OUT_DIM + k] : 0.f;
            c *= 0.1f;
            for (int s = 0; s < T_STEPS; ++s) {
                v = v * LEAK + c;
                if (v >= 1.0f) { bo = b; break; }
            }
        }
        out[(size_t)g * OUT_DIM + k] = (bo == g) ? 0.1f : 0.f;
    }
}

// ---------------------------------------------------------------------------
extern "C" void kernel_launch(void* const* d_in, const int* in_sizes, int n_in,
                              void* d_out, int out_size, void* d_ws, size_t ws_size,
                              hipStream_t stream) {
    const float* x    = (const float*)d_in[0];  // [512, 4096]
    const float* W_ih = (const float*)d_in[1];  // [4096, 8192]
    const float* W_ho = (const float*)d_in[2];  // [8192, 1024]
    float* out = (float*)d_out;                 // [512, 1024] fp32

    char* base = (char*)d_ws;
    int* bfire_h = (int*)(base + 29360128);     // 32 KB (rewritten each launch)
    int* hflag   = (int*)(base + 29393920);     // 2 KB
    int* bo_fast = (int*)(base + 29396992);     // 4 KB

    hidden_k<<<512, 256, 0, stream>>>(x, W_ih, W_ho, bfire_h, hflag, bo_fast);
    final_k<<<512, 256, 0, stream>>>(W_ho, bfire_h, hflag, bo_fast, out);
}

// Round 7
// 179.507 us; speedup vs baseline: 1.2756x; 1.0058x over previous
//
#include <hip/hip_runtime.h>
#include <math.h>

#define BATCH   512
#define IN_DIM  4096
#define HID_DIM 8192
#define OUT_DIM 1024
#define T_STEPS 10
#define LEAK    0.95f

// ===========================================================================
// SINGLE plain dispatch, 256 blocks x 256 threads, ZERO workspace use
// (inherently poison-safe). Block g owns output rows {2g, 2g+1}.
//
// Exactness argument (validated by absmax=0.0 in rounds 3-6):
//  * REFRACT=1 and current_time=spike_count imply each neuron spikes AT MOST
//    ONCE EVER (after a spike, t-last==1 forever, never >1); adaptation
//    (count>10) unreachable. Per-neuron result = index of first batch whose
//    constant current drives v over threshold within 10 leaky steps
//    (fires iff c >= (1-LEAK)/(1-LEAK^10) = 0.12461).
//  * Weights >= 0 (clip[0,1]) and rates > 0, so partial row-sums LOWER-BOUND
//    currents. Each block verifies ALL 8192 hidden columns fire at b=0 via
//    an adaptive lb sweep (4 rows/step, wave-__all early exit, <=64 rows;
//    typical exit at 4 rows, E[lb]~2 vs 0.125 threshold). Redundant per
//    block, but the rows are L2-resident (~33 MB aggregate, ~1 us).
//  * All-hidden-at-b0  =>  output currents are 0 for b>0  =>  rows g>=1 are
//    identically zero (no Who data needed). Row 0 (block 0 only): bo[k]=0
//    iff 0.1*colsum(W_ho[:,k]) >= 0.12461; adaptive lb, exact full colsum
//    for any column whose lb fails.
//  * Any hidden-check failure => exact in-block fallback (recomputes all
//    hidden spike indices and this block's rows from scratch; slow,
//    correctness-only, never taken on bench data).
// ===========================================================================
__global__ __launch_bounds__(256) void snn_one(const float* __restrict__ x,
                                               const float* __restrict__ Wih,
                                               const float* __restrict__ Who,
                                               float* __restrict__ out) {
    __shared__ float rs[64];
    __shared__ int votes[4];

    const int bid = blockIdx.x;   // 256
    const int t = threadIdx.x;    // 256

    // rates of x row 0, rows 0..63
    if (t < 64) rs[t] = 1.f / (1.f + __expf(-x[t]));
    __syncthreads();

    // ---- adaptive hidden lower-bound check: thread owns cols t+256q ----
    float acc[32];
#pragma unroll
    for (int q = 0; q < 32; ++q) acc[q] = 0.f;
    bool ok = false;
    for (int r = 0; r < 64 && !ok; r += 4) {
#pragma unroll
        for (int rr = 0; rr < 4; ++rr) {
            const float rate = rs[r + rr];
            const float* wrow = Wih + (size_t)(r + rr) * HID_DIM + t;
#pragma unroll
            for (int q = 0; q < 32; ++q)
                acc[q] += rate * wrow[q * 256];
        }
        bool myok = true;
#pragma unroll
        for (int q = 0; q < 32; ++q) myok &= (acc[q] >= 0.125f);
        ok = __all((int)myok);
    }
    if ((t & 63) == 0) votes[t >> 6] = ok ? 1 : 0;
    __syncthreads();
    const bool fast = votes[0] && votes[1] && votes[2] && votes[3];

    if (fast) {
        const float4 z = {0.f, 0.f, 0.f, 0.f};
        if (bid == 0) {
            // row 0: per-column output verdict (bo in {0,-1} in this regime)
#pragma unroll
            for (int kq = 0; kq < 4; ++kq) {
                const int k = kq * 256 + t;
                float a = 0.f;
                bool p = false;
                for (int r = 0; r < 64 && !p; r += 4) {
#pragma unroll
                    for (int rr = 0; rr < 4; ++rr)
                        a += Who[(size_t)(r + rr) * OUT_DIM + k];
                    p = (a >= 1.25f);          // 0.1*colsum >= 0.125
                }
                int bo;
                if (p) {
                    bo = 0;
                } else {
                    // exact full colsum + 10-step simulation
                    float full = 0.f;
                    for (int j = 0; j < HID_DIM; ++j)
                        full += Who[(size_t)j * OUT_DIM + k];
                    full *= 0.1f;
                    float v = 0.f;
                    bo = -1;
#pragma unroll
                    for (int s = 0; s < T_STEPS; ++s) {
                        v = v * LEAK + full;
                        if (v >= 1.0f) { bo = 0; break; }
                    }
                }
                out[k] = (bo == 0) ? 0.1f : 0.f;
            }
            ((float4*)out)[256 + t] = z;                      // row 1 = 0
        } else {
            ((float4*)out)[(size_t)(bid * 2) * 256 + t] = z;  // row 2g = 0
            ((float4*)out)[(size_t)(bid * 2 + 1) * 256 + t] = z;
        }
        return;
    }

    // ======================================================================
    // EXACT in-block fallback (correctness-only; never runs on bench data).
    // Recompute every hidden neuron's firing batch, then this block's rows.
    // ======================================================================
    __shared__ float rsb[IN_DIM];     // 16 KB
    __shared__ int bfh[HID_DIM];      // 32 KB
    for (int q = 0; q < 32; ++q) {
        const int j = q * 256 + t;
        float v = 0.f;
        int bf = -1;
        for (int b = 0; b < BATCH; ++b) {
            for (int i = t; i < IN_DIM; i += 256)
                rsb[i] = 1.f / (1.f + __expf(-x[(size_t)b * IN_DIM + i]));
            __syncthreads();
            if (bf < 0) {
                float c = 0.f;
                for (int i = 0; i < IN_DIM; ++i)
                    c += rsb[i] * Wih[(size_t)i * HID_DIM + j];
                for (int s = 0; s < T_STEPS; ++s) {
                    v = v * LEAK + c;
                    if (v >= 1.0f) { bf = b; break; }     // single-spike structure
                }
            }
            if (__syncthreads_and(bf >= 0)) break;
        }
        bfh[j] = bf;
        __syncthreads();
    }
    for (int row = 0; row < 2; ++row) {
        const int g = bid * 2 + row;
#pragma unroll
        for (int kq = 0; kq < 4; ++kq) {
            const int k = kq * 256 + t;
            float v = 0.f;
            int bo = -1;
            for (int b = 0; b < BATCH && bo < 0; ++b) {
                float c = 0.f;
                for (int j = 0; j < HID_DIM; ++j)
                    if (bfh[j] == b) c += Who[(size_t)j * OUT_DIM + k];
                c *= 0.1f;
                for (int s = 0; s < T_STEPS; ++s) {
                    v = v * LEAK + c;
                    if (v >= 1.0f) { bo = b; break; }
                }
            }
            out[(size_t)g * OUT_DIM + k] = (bo == g) ? 0.1f : 0.f;
        }
    }
}

// ---------------------------------------------------------------------------
extern "C" void kernel_launch(void* const* d_in, const int* in_sizes, int n_in,
                              void* d_out, int out_size, void* d_ws, size_t ws_size,
                              hipStream_t stream) {
    const float* x    = (const float*)d_in[0];  // [512, 4096]
    const float* W_ih = (const float*)d_in[1];  // [4096, 8192]
    const float* W_ho = (const float*)d_in[2];  // [8192, 1024]
    float* out = (float*)d_out;                 // [512, 1024] fp32

    (void)d_ws; (void)ws_size;                  // no workspace: poison-proof

    snn_one<<<256, 256, 0, stream>>>(x, W_ih, W_ho, out);
}